// Round 19
// baseline (606.356 us; speedup 1.0000x reference)
//
#include <hip/hip_runtime.h>
#include <stdint.h>

// HashEncoder (Instant-NGP / HashNeRF): 1M points, 16 levels, 2 feats, 2^19 table.
// R17: k_enc 2-points-per-thread probe. R16 landed 547.7us (beats 554.7 baseline):
//   k_enc 365.5us, FETCH 379MB == 8-XCD replication floor (Sum footprints ~396MB),
//   WRITE 131MB exact; k_tr ~37-70us (at its ~41us floor after block-contiguous ws;
//   old "190us" was mostly the ~110-145us fixed harness overhead).
// k_enc mechanism question: 8.2GB of L2->L1 line fills run at 22.5TB/s = 65% of
// the 34.5TB/s L2 ceiling. Either (a) line-fill-bound (365 is structural) or
// (b) wave-issue/VALU overhead contributes (VALUBusy 27.6%, 2M wave-gathers).
// This round: 2 pts/thread — halves waves, amortizes level constants + x addr,
// 16B ws stores, same gather count/layouts. If (b): k_enc -> 310-345. If (a):
// unchanged — then we're at the structural limit and the session closes.
// R18/R19: unchanged — R17 never ran (container failures); the probe must land.

static constexpr int NP = 1048576;
static constexpr int NL = 16;
static constexpr int TPB = 256;
static constexpr uint32_t HMASK = (1u << 19) - 1u;

typedef float f32x4 __attribute__((ext_vector_type(4)));

// res_i = floor(16 * b^i), b = f32(exp((ln512-ln16)/15)) = 1.2599210739135742
// Verified: absmax 2.4e-7 vs reference (R8-R11, R16 runs).
__constant__ float c_res[NL] = {16.f, 20.f, 25.f, 32.f, 40.f, 50.f, 64.f, 80.f,
                                101.f, 128.f, 161.f, 203.f, 256.f, 322.f, 406.f, 512.f};

__device__ __forceinline__ float2 enc_one(
    float x0, float x1, float x2,
    float b0, float b1, float b2,
    float B0, float B1, float B2,
    const float2* __restrict__ tab, float res, float gate)
{
    // index path must be bit-exact vs numpy f32: sub/div/floor only
    float g0 = (B0 - b0) / res;
    float g1 = (B1 - b1) / res;
    float g2 = (B2 - b2) / res;
    float xc0 = fminf(fmaxf(x0, b0), B0);
    float xc1 = fminf(fmaxf(x1, b1), B1);
    float xc2 = fminf(fmaxf(x2, b2), B2);
    float f0 = floorf((xc0 - b0) / g0);
    float f1 = floorf((xc1 - b1) / g1);
    float f2 = floorf((xc2 - b2) / g2);
    // interpolation weights use RAW x (per reference)
    float v0 = f0 * g0 + b0;
    float v1 = f1 * g1 + b1;
    float v2 = f2 * g2 + b2;
    float w0 = (x0 - v0) / ((v0 + g0) - v0);
    float w1 = (x1 - v1) / ((v1 + g1) - v1);
    float w2 = (x2 - v2) / ((v2 + g2) - v2);

    uint32_t u0 = (uint32_t)(int)f0;
    uint32_t u1 = (uint32_t)(int)f1;
    uint32_t u2 = (uint32_t)(int)f2;
    uint32_t ya = u1 * 2654435761u, yb = (u1 + 1u) * 2654435761u;
    uint32_t za = u2 * 805459861u,  zb = (u2 + 1u) * 805459861u;
    uint32_t xa = u0, xb = u0 + 1u;

    // corner index = i*4 + j*2 + k (i on x, j on y, k on z)
    float2 e000 = tab[(xa ^ ya ^ za) & HMASK];
    float2 e001 = tab[(xa ^ ya ^ zb) & HMASK];
    float2 e010 = tab[(xa ^ yb ^ za) & HMASK];
    float2 e011 = tab[(xa ^ yb ^ zb) & HMASK];
    float2 e100 = tab[(xb ^ ya ^ za) & HMASK];
    float2 e101 = tab[(xb ^ ya ^ zb) & HMASK];
    float2 e110 = tab[(xb ^ yb ^ za) & HMASK];
    float2 e111 = tab[(xb ^ yb ^ zb) & HMASK];

    float s0 = 1.f - w0, s1 = 1.f - w1, s2 = 1.f - w2;
    float cx00x = e000.x * s0 + e100.x * w0, cx00y = e000.y * s0 + e100.y * w0;
    float cx01x = e001.x * s0 + e101.x * w0, cx01y = e001.y * s0 + e101.y * w0;
    float cx10x = e010.x * s0 + e110.x * w0, cx10y = e010.y * s0 + e110.y * w0;
    float cx11x = e011.x * s0 + e111.x * w0, cx11y = e011.y * s0 + e111.y * w0;
    float c0x = cx00x * s1 + cx10x * w1, c0y = cx00y * s1 + cx10y * w1;
    float c1x = cx01x * s1 + cx11x * w1, c1y = cx01y * s1 + cx11y * w1;
    float ox = c0x * s2 + c1x * w2;
    float oy = c0y * s2 + c1y * w2;
    return make_float2(ox * gate, oy * gate);
}

// Kernel 1: thread = (2 consecutive points, level). blockIdx.y = level keeps the
// verified level-major dispatch (one ~4MB table hot per XCD L2). Block covers 512
// points = two 256-pt chunks of ws. Store: one f32x4 (points 2t,2t+1 adjacent in
// [chunk][level][pt] layout) — 1KB contiguous per wave.
__global__ __launch_bounds__(TPB) void k_enc2(
    const float* __restrict__ x, const float* __restrict__ emb,
    const float* __restrict__ lw, const float* __restrict__ bmin,
    const float* __restrict__ bmax, f32x4* __restrict__ ws4)
{
    int t = threadIdx.x;
    int l = blockIdx.y;
    int P = blockIdx.x * 512 + 2 * t;        // first of two points

    float b0 = bmin[0], b1 = bmin[1], b2 = bmin[2];
    float B0 = bmax[0], B1 = bmax[1], B2 = bmax[2];
    float res = c_res[l];
    float gate = 1.0f / (1.0f + expf(-lw[l]));
    const float2* tab = (const float2*)(emb + ((size_t)l << 20));

    float xa0 = x[3 * P + 0], xa1 = x[3 * P + 1], xa2 = x[3 * P + 2];
    float xb0 = x[3 * P + 3], xb1 = x[3 * P + 4], xb2 = x[3 * P + 5];

    float2 ra = enc_one(xa0, xa1, xa2, b0, b1, b2, B0, B1, B2, tab, res, gate);
    float2 rb = enc_one(xb0, xb1, xb2, b0, b1, b2, B0, B1, B2, tab, res, gate);

    // ws float2-index for point P, level l: (P>>8)*4096 + l*256 + (P&255).
    // P even, P&255 even -> f32x4 index = half that.
    size_t f2i = ((size_t)(P >> 8)) * 4096 + (size_t)l * 256 + (P & 255);
    f32x4 v = {ra.x, ra.y, rb.x, rb.y};
    ws4[f2i >> 1] = v;
}

// Kernel 2: transpose, pure streaming (R16-verified). Block = 256 points.
__global__ __launch_bounds__(TPB) void k_tr(
    const f32x4* __restrict__ ws4, f32x4* __restrict__ out)
{
    __shared__ float2 s[256][17];
    int t = threadIdx.x;
    size_t b = (size_t)blockIdx.x;
#pragma unroll
    for (int k = 0; k < 8; ++k) {
        int j = k * 256 + t;          // 0..2047 f32x4 within chunk
        f32x4 v = ws4[b * 2048 + (size_t)j];
        int l = j >> 7;               // level
        int u = 2 * (j & 127);        // first of two points
        s[u][l]     = make_float2(v.x, v.y);
        s[u + 1][l] = make_float2(v.z, v.w);
    }
    __syncthreads();
    size_t p0 = b * 256;
#pragma unroll
    for (int k = 0; k < 8; ++k) {
        int n = k * 256 + t;          // 0..2047: f32x4 index within block tile
        int q = n >> 3;               // local point
        int j = n & 7;                // quad within point
        float2 a = s[q][2 * j];
        float2 c = s[q][2 * j + 1];
        f32x4 v = {a.x, a.y, c.x, c.y};
        out[p0 * 8 + (size_t)n] = v;
    }
}

// Fallback if ws too small: R8 fused kernel (verified correct, 615us).
__global__ __launch_bounds__(TPB) void k_enc_fused(
    const float* __restrict__ x, const float* __restrict__ emb,
    const float* __restrict__ lw, const float* __restrict__ bmin,
    const float* __restrict__ bmax, f32x4* __restrict__ out)
{
    __shared__ float2 s[TPB][9];
    int t = threadIdx.x;
    size_t p0 = (size_t)blockIdx.x * TPB;
    int p = (int)p0 + t;

    float x0 = x[3 * p + 0], x1 = x[3 * p + 1], x2 = x[3 * p + 2];
    float b0 = bmin[0], b1 = bmin[1], b2 = bmin[2];
    float B0 = bmax[0], B1 = bmax[1], B2 = bmax[2];

#pragma unroll
    for (int ph = 0; ph < 2; ++ph) {
        if (ph) __syncthreads();
#pragma unroll
        for (int m = 0; m < 8; ++m) {
            int l = ph * 8 + m;
            float res = c_res[l];
            float gate = 1.0f / (1.0f + expf(-lw[l]));
            const float2* tab = (const float2*)(emb + ((size_t)l << 20));
            s[t][m] = enc_one(x0, x1, x2, b0, b1, b2, B0, B1, B2, tab, res, gate);
        }
        __syncthreads();
#pragma unroll
        for (int k = 0; k < 4; ++k) {
            int n = k * TPB + t;
            int q = n >> 2;
            int j = n & 3;
            float2 a = s[q][2 * j];
            float2 c = s[q][2 * j + 1];
            f32x4 v = {a.x, a.y, c.x, c.y};
            out[(p0 + (size_t)q) * 8 + ph * 4 + j] = v;
        }
    }
}

extern "C" void kernel_launch(void* const* d_in, const int* in_sizes, int n_in,
                              void* d_out, int out_size, void* d_ws, size_t ws_size,
                              hipStream_t stream) {
    const float* x    = (const float*)d_in[0];
    const float* emb  = (const float*)d_in[1];
    const float* lw   = (const float*)d_in[2];
    const float* bmin = (const float*)d_in[3];
    const float* bmax = (const float*)d_in[4];

    const size_t ws_need = (size_t)NL * NP * sizeof(float2);  // 128 MB
    if (ws_size >= ws_need) {
        dim3 grid1(NP / 512, NL);
        k_enc2<<<grid1, TPB, 0, stream>>>(x, emb, lw, bmin, bmax, (f32x4*)d_ws);
        k_tr<<<NP / 256, TPB, 0, stream>>>((const f32x4*)d_ws, (f32x4*)d_out);
    } else {
        k_enc_fused<<<NP / TPB, TPB, 0, stream>>>(
            x, emb, lw, bmin, bmax, (f32x4*)d_out);
    }
}

// Round 20
// 547.777 us; speedup vs baseline: 1.1069x; 1.1069x over previous
//
#include <hip/hip_runtime.h>
#include <stdint.h>

// HashEncoder (Instant-NGP / HashNeRF): 1M points, 16 levels, 2 feats, 2^19 table.
// R20 FINAL: restore R16 (best verified: 547.7us bench; beats 554.7 baseline).
// Session conclusions (all measured):
//  - k_enc (thread=(pt,level), blockIdx.y=level): 365.5us. FETCH 379MB == 8-XCD
//    table-replication floor; WRITE 131MB exact; 0 bank conflicts; occ 87%.
//    Gather is L2-miss-LATENCY-bound at max wave concurrency: R19's 2-pt/thread
//    probe (half waves, 2x ILP) regressed to 427us (VALUBusy 27.6->19.6% yet
//    slower) -> throughput scales with resident waves; already at max.
//    Ideal L1-addr-rate floor ~208us; 365us = 57% with L2 latency filling gap.
//  - k_tr with block-contiguous ws ([chunk][level][pt]): at its ~41us streaming
//    floor (absent from top-5 dispatches; old "190us" was harness overhead).
//  - Regressed alternatives: fused in-thread loop 615 (L2 drift, FETCH 2.0GB);
//    XCD level-pairing 740 (2 tables > 4MiB L2 + imbalance); 16 launches 707
//    (+250us launch overhead); direct-scatter nt stores 780 (sub-32B store path
//    ~3x its traffic model). ~120us of bench dur is fixed harness overhead.

static constexpr int NP = 1048576;
static constexpr int NL = 16;
static constexpr int TPB = 256;
static constexpr uint32_t HMASK = (1u << 19) - 1u;

typedef float f32x4 __attribute__((ext_vector_type(4)));

// res_i = floor(16 * b^i), b = f32(exp((ln512-ln16)/15)) = 1.2599210739135742
// Verified: absmax 2.4e-7 vs reference (R8-R11, R16, R19 runs).
__constant__ float c_res[NL] = {16.f, 20.f, 25.f, 32.f, 40.f, 50.f, 64.f, 80.f,
                                101.f, 128.f, 161.f, 203.f, 256.f, 322.f, 406.f, 512.f};

__device__ __forceinline__ float2 enc_one(
    float x0, float x1, float x2,
    float b0, float b1, float b2,
    float B0, float B1, float B2,
    const float2* __restrict__ tab, float res, float gate)
{
    // index path must be bit-exact vs numpy f32: sub/div/floor only
    float g0 = (B0 - b0) / res;
    float g1 = (B1 - b1) / res;
    float g2 = (B2 - b2) / res;
    float xc0 = fminf(fmaxf(x0, b0), B0);
    float xc1 = fminf(fmaxf(x1, b1), B1);
    float xc2 = fminf(fmaxf(x2, b2), B2);
    float f0 = floorf((xc0 - b0) / g0);
    float f1 = floorf((xc1 - b1) / g1);
    float f2 = floorf((xc2 - b2) / g2);
    // interpolation weights use RAW x (per reference)
    float v0 = f0 * g0 + b0;
    float v1 = f1 * g1 + b1;
    float v2 = f2 * g2 + b2;
    float w0 = (x0 - v0) / ((v0 + g0) - v0);
    float w1 = (x1 - v1) / ((v1 + g1) - v1);
    float w2 = (x2 - v2) / ((v2 + g2) - v2);

    uint32_t u0 = (uint32_t)(int)f0;
    uint32_t u1 = (uint32_t)(int)f1;
    uint32_t u2 = (uint32_t)(int)f2;
    uint32_t ya = u1 * 2654435761u, yb = (u1 + 1u) * 2654435761u;
    uint32_t za = u2 * 805459861u,  zb = (u2 + 1u) * 805459861u;
    uint32_t xa = u0, xb = u0 + 1u;

    // corner index = i*4 + j*2 + k (i on x, j on y, k on z)
    float2 e000 = tab[(xa ^ ya ^ za) & HMASK];
    float2 e001 = tab[(xa ^ ya ^ zb) & HMASK];
    float2 e010 = tab[(xa ^ yb ^ za) & HMASK];
    float2 e011 = tab[(xa ^ yb ^ zb) & HMASK];
    float2 e100 = tab[(xb ^ ya ^ za) & HMASK];
    float2 e101 = tab[(xb ^ ya ^ zb) & HMASK];
    float2 e110 = tab[(xb ^ yb ^ za) & HMASK];
    float2 e111 = tab[(xb ^ yb ^ zb) & HMASK];

    float s0 = 1.f - w0, s1 = 1.f - w1, s2 = 1.f - w2;
    float cx00x = e000.x * s0 + e100.x * w0, cx00y = e000.y * s0 + e100.y * w0;
    float cx01x = e001.x * s0 + e101.x * w0, cx01y = e001.y * s0 + e101.y * w0;
    float cx10x = e010.x * s0 + e110.x * w0, cx10y = e010.y * s0 + e110.y * w0;
    float cx11x = e011.x * s0 + e111.x * w0, cx11y = e011.y * s0 + e111.y * w0;
    float c0x = cx00x * s1 + cx10x * w1, c0y = cx00y * s1 + cx10y * w1;
    float c1x = cx01x * s1 + cx11x * w1, c1y = cx01y * s1 + cx11y * w1;
    float ox = c0x * s2 + c1x * w2;
    float oy = c0y * s2 + c1y * w2;
    return make_float2(ox * gate, oy * gate);
}

// Kernel 1: thread = (point, level). blockIdx.y = level -> level-major dispatch
// order, one ~4MB table hot per XCD L2 (verified 365us; FETCH at replication
// floor). ws layout [chunk=p>>8][level][pt&255]: store bx*4096 + l*256 + t,
// contiguous 512B per wave.
__global__ __launch_bounds__(TPB) void k_enc(
    const float* __restrict__ x, const float* __restrict__ emb,
    const float* __restrict__ lw, const float* __restrict__ bmin,
    const float* __restrict__ bmax, float2* __restrict__ ws)
{
    int t = threadIdx.x;
    int p = blockIdx.x * TPB + t;
    int l = blockIdx.y;
    float x0 = x[3 * p + 0], x1 = x[3 * p + 1], x2 = x[3 * p + 2];
    float b0 = bmin[0], b1 = bmin[1], b2 = bmin[2];
    float B0 = bmax[0], B1 = bmax[1], B2 = bmax[2];
    float res = c_res[l];
    float gate = 1.0f / (1.0f + expf(-lw[l]));
    const float2* tab = (const float2*)(emb + ((size_t)l << 20));
    float2 r = enc_one(x0, x1, x2, b0, b1, b2, B0, B1, B2, tab, res, gate);
    ws[(size_t)blockIdx.x * 4096 + l * 256 + t] = r;
}

// Kernel 2: transpose, pure streaming (verified at ~floor). Block = 256 points =
// one 32KB contiguous chunk in, 32KB contiguous out.
__global__ __launch_bounds__(TPB) void k_tr(
    const f32x4* __restrict__ ws4, f32x4* __restrict__ out)
{
    __shared__ float2 s[256][17];
    int t = threadIdx.x;
    size_t b = (size_t)blockIdx.x;
#pragma unroll
    for (int k = 0; k < 8; ++k) {
        int j = k * 256 + t;          // 0..2047 f32x4 within chunk
        f32x4 v = ws4[b * 2048 + (size_t)j];
        int l = j >> 7;               // level
        int u = 2 * (j & 127);        // first of two points
        s[u][l]     = make_float2(v.x, v.y);
        s[u + 1][l] = make_float2(v.z, v.w);
    }
    __syncthreads();
    size_t p0 = b * 256;
#pragma unroll
    for (int k = 0; k < 8; ++k) {
        int n = k * 256 + t;          // 0..2047: f32x4 index within block tile
        int q = n >> 3;               // local point
        int j = n & 7;                // quad within point
        float2 a = s[q][2 * j];
        float2 c = s[q][2 * j + 1];
        f32x4 v = {a.x, a.y, c.x, c.y};
        out[p0 * 8 + (size_t)n] = v;
    }
}

// Fallback if ws too small: R8 fused kernel (verified correct, 615us).
__global__ __launch_bounds__(TPB) void k_enc_fused(
    const float* __restrict__ x, const float* __restrict__ emb,
    const float* __restrict__ lw, const float* __restrict__ bmin,
    const float* __restrict__ bmax, f32x4* __restrict__ out)
{
    __shared__ float2 s[TPB][9];
    int t = threadIdx.x;
    size_t p0 = (size_t)blockIdx.x * TPB;
    int p = (int)p0 + t;

    float x0 = x[3 * p + 0], x1 = x[3 * p + 1], x2 = x[3 * p + 2];
    float b0 = bmin[0], b1 = bmin[1], b2 = bmin[2];
    float B0 = bmax[0], B1 = bmax[1], B2 = bmax[2];

#pragma unroll
    for (int ph = 0; ph < 2; ++ph) {
        if (ph) __syncthreads();
#pragma unroll
        for (int m = 0; m < 8; ++m) {
            int l = ph * 8 + m;
            float res = c_res[l];
            float gate = 1.0f / (1.0f + expf(-lw[l]));
            const float2* tab = (const float2*)(emb + ((size_t)l << 20));
            s[t][m] = enc_one(x0, x1, x2, b0, b1, b2, B0, B1, B2, tab, res, gate);
        }
        __syncthreads();
#pragma unroll
        for (int k = 0; k < 4; ++k) {
            int n = k * TPB + t;
            int q = n >> 2;
            int j = n & 3;
            float2 a = s[q][2 * j];
            float2 c = s[q][2 * j + 1];
            f32x4 v = {a.x, a.y, c.x, c.y};
            out[(p0 + (size_t)q) * 8 + ph * 4 + j] = v;
        }
    }
}

extern "C" void kernel_launch(void* const* d_in, const int* in_sizes, int n_in,
                              void* d_out, int out_size, void* d_ws, size_t ws_size,
                              hipStream_t stream) {
    const float* x    = (const float*)d_in[0];
    const float* emb  = (const float*)d_in[1];
    const float* lw   = (const float*)d_in[2];
    const float* bmin = (const float*)d_in[3];
    const float* bmax = (const float*)d_in[4];

    const size_t ws_need = (size_t)NL * NP * sizeof(float2);  // 128 MB
    if (ws_size >= ws_need) {
        dim3 grid1(NP / TPB, NL);
        k_enc<<<grid1, TPB, 0, stream>>>(x, emb, lw, bmin, bmax, (float2*)d_ws);
        k_tr<<<NP / 256, TPB, 0, stream>>>((const f32x4*)d_ws, (f32x4*)d_out);
    } else {
        k_enc_fused<<<NP / TPB, TPB, 0, stream>>>(
            x, emb, lw, bmin, bmax, (f32x4*)d_out);
    }
}